// Round 7
// baseline (160.665 us; speedup 1.0000x reference)
//
#include <hip/hip_runtime.h>
#include <hip/hip_bf16.h>
#include <math.h>

#define NN 1024

typedef __attribute__((ext_vector_type(8))) short bf16x8;
typedef __attribute__((ext_vector_type(4))) float f32x4;

__device__ __forceinline__ float wave_sum(float v) {
#pragma unroll
  for (int off = 32; off > 0; off >>= 1) v += __shfl_down(v, off);
  return v;
}
__device__ __forceinline__ float wave_max(float v) {
#pragma unroll
  for (int off = 32; off > 0; off >>= 1) v = fmaxf(v, __shfl_down(v, off));
  return v;
}
__device__ __forceinline__ short f2bf(float x) {
  __hip_bfloat16 b = __float2bfloat16(x);
  return *(short*)&b;
}

#define SH_C0 0.28209479177387814f
#define SH_C1 0.4886025119029199f
#define SH_S15 1.0925484305920792f
#define SH_S5 0.6307831305050401f

// ---------------------------------------------------------------------------
// K1: fused independent staging. Block ranges:
//   [0,8)        : 8 weight mats fp32 -> bf16 (order q,k,v0,v1,v2,o0,o1,o2)
//   [8,1160)     : x_emb -> bf16 (x_bf, MFMA-A layout = original layout)
//   [1160,1448)  : fT[c][k=m*1024+i] bf16 (LDS tile transpose)
//   [1448,2472)  : Wpack: sh*idg*valid in MFMA-A FRAGMENT order —
//                  element (j,k) at (jg*288+kt)*512 + (kq*16+jr)*8 + ke,
//                  jg=j>>4 jr=j&15 kt=k>>5 kq=(k>>3)&3 ke=k&7. This makes
//                  colmean's A-load one contiguous 1KB segment per wave
//                  (the R1-R6 form was a 64-line gather per load — the
//                  dominant colmean cost by elimination, R2/R3/R5/R6).
//   [2472,3496)  : row stats + fused rowmean -> rowm_bf (bf16)
__global__ __launch_bounds__(256) void htr_geom(
    const float* __restrict__ qw, const float* __restrict__ kw,
    const float* __restrict__ vw, const float* __restrict__ ow,
    const float* __restrict__ x_emb, const float* __restrict__ pos,
    const int* __restrict__ batch, short* __restrict__ wbf,
    short* __restrict__ x_bf, short* __restrict__ fT,
    short* __restrict__ Wpack, short* __restrict__ rowm_bf) {
  const int b = blockIdx.x;
  const int tid = threadIdx.x;
  __shared__ short tile[128][34];
  __shared__ float red[4][9];
  __shared__ float sm[9];

  if (b < 8) {
    const float* src;
    if (b == 0) src = qw;
    else if (b == 1) src = kw;
    else if (b < 5) src = vw + (b - 2) * 16384;
    else src = ow + (b - 5) * 16384;
    short* dst = wbf + b * 16384;
    for (int idx = tid; idx < 16384; idx += 256) dst[idx] = f2bf(src[idx]);
  } else if (b < 1160) {
    int base = (b - 8) * 1024 + tid * 4;
    float4 v = *(const float4*)(x_emb + base);
    *(short4*)(x_bf + base) = make_short4(f2bf(v.x), f2bf(v.y), f2bf(v.z), f2bf(v.w));
  } else if (b < 1448) {
    const int sub = b - 1160;
    const int i0 = (sub & 31) * 32;
    const int m = sub >> 5;
#pragma unroll
    for (int it = 0; it < 16; ++it) {
      int e = tid + it * 256;
      int r = e >> 7, c = e & 127;
      tile[c][r] = f2bf(x_emb[((i0 + r) * 9 + m) * 128 + c]);
    }
    __syncthreads();
#pragma unroll
    for (int it = 0; it < 8; ++it) {
      int idx = tid + it * 256;
      int c = idx >> 4, ii2 = idx & 15;
      *(short2*)(fT + c * 9216 + m * 1024 + i0 + ii2 * 2) =
          make_short2(tile[c][ii2 * 2], tile[c][ii2 * 2 + 1]);
    }
  } else if (b < 2472) {
    const int j = b - 1448;
    const int jg = j >> 4, jr = j & 15;
    const float pjx = pos[j * 3 + 0], pjy = pos[j * 3 + 1], pjz = pos[j * 3 + 2];
    const int bj = batch[j];
    for (int i = tid; i < 1024; i += 256) {
      float dx = pos[i * 3 + 0] - pjx;
      float dy = pos[i * 3 + 1] - pjy;
      float dz = pos[i * 3 + 2] - pjz;
      bool ok = (i != j) && (batch[i] == bj);
      float okf = ok ? 1.f : 0.f;
      float d2 = dx * dx + dy * dy + dz * dz;
      float inv = okf / fmaxf(sqrtf(d2), 1e-8f);
      float x = dx * inv, y = dy * inv, z = dz * inv;
      // fragment-slot base for (j, k = m*1024 + i):
      // kt = m*32 + (i>>5), kq = (i>>3)&3, ke = i&7
      const int kq = (i >> 3) & 3, ke = i & 7, it5 = i >> 5;
      short* wp = Wpack + jg * 147456 + it5 * 512 + (kq * 16 + jr) * 8 + ke;
      wp[0 * 16384] = f2bf(SH_C0 * okf);
      wp[1 * 16384] = f2bf((SH_C1 * (1.f / 3.f)) * x);
      wp[2 * 16384] = f2bf((SH_C1 * (1.f / 3.f)) * y);
      wp[3 * 16384] = f2bf((SH_C1 * (1.f / 3.f)) * z);
      wp[4 * 16384] = f2bf((SH_S15 * 0.2f) * x * z);
      wp[5 * 16384] = f2bf((SH_S15 * 0.2f) * x * y);
      wp[6 * 16384] = f2bf((SH_S5 * 0.2f) * (y * y - 0.5f * (x * x + z * z)));
      wp[7 * 16384] = f2bf((SH_S15 * 0.2f) * y * z);
      wp[8 * 16384] = f2bf((0.5f * SH_S15 * 0.2f) * (z * z - x * x));
    }
  } else {
    const int i = b - 2472;
    const float px = pos[i * 3 + 0], py = pos[i * 3 + 1], pz = pos[i * 3 + 2];
    const int bi = batch[i];
    float s[9];
#pragma unroll
    for (int m = 0; m < 9; ++m) s[m] = 0.f;
    for (int j = tid; j < NN; j += 256) {
      if (j == i) continue;
      if (batch[j] != bi) continue;
      float dx = px - pos[j * 3 + 0];
      float dy = py - pos[j * 3 + 1];
      float dz = pz - pos[j * 3 + 2];
      float d2 = dx * dx + dy * dy + dz * dz;
      float inv = 1.0f / fmaxf(sqrtf(d2), 1e-8f);
      float x = dx * inv, y = dy * inv, z = dz * inv;
      s[0] += 1.0f;
      s[1] += x; s[2] += y; s[3] += z;
      s[4] += x * z; s[5] += x * y;
      s[6] += y * y - 0.5f * (x * x + z * z);
      s[7] += y * z;
      s[8] += z * z - x * x;
    }
    const int wave = tid >> 6, lane = tid & 63;
#pragma unroll
    for (int m = 0; m < 9; ++m) {
      float v = wave_sum(s[m]);
      if (lane == 0) red[wave][m] = v;
    }
    __syncthreads();
    if (tid < 9) {
      float v = red[0][tid] + red[1][tid] + red[2][tid] + red[3][tid];
      float scl = SH_S15 * 0.2f;
      if (tid == 0) scl = SH_C0;
      else if (tid < 4) scl = SH_C1 * (1.f / 3.f);
      else if (tid == 6) scl = SH_S5 * 0.2f;
      else if (tid == 8) scl = 0.5f * SH_S15 * 0.2f;
      sm[tid] = v * scl * (1.0f / 1024.0f);
    }
    __syncthreads();
    if (tid < 128) {
      float acc = 0.f;
#pragma unroll
      for (int m = 0; m < 9; ++m)
        acc = fmaf(sm[m], x_emb[(i * 9 + m) * 128 + tid], acc);
      rowm_bf[i * 128 + tid] = f2bf(acc);
    }
  }
}

// ---------------------------------------------------------------------------
// K2 v5: colmean partial GEMM, 4-wave blocks, LDS-staged fT (coalesced)
// + fragment-ordered Wpack A-loads (coalesced: 1KB contiguous per wave).
// part[ks][j][c] = sum over k-chunk of shW(j,k)*fT[c][k].
#define CMS 16
__global__ __launch_bounds__(256) void htr_colmean_mfma(
    const short* __restrict__ Wpack, const short* __restrict__ fT,
    float* __restrict__ part) {
  const int jb = blockIdx.x * 64;
  const int ks = blockIdx.y;
  const int tid = threadIdx.x;
  const int w = tid >> 6, lane = tid & 63;
  const int q = lane >> 4, l15 = lane & 15;
  __shared__ short bt[32][584];

  // A-fragments: jg = jb/16 + w, k-tiles ks*18 .. +17; contiguous per wave.
  const int jg = blockIdx.x * 4 + w;
  const short* ap = Wpack + (jg * 288 + ks * 18) * 512 + lane * 8;
  bf16x8 A[18];
#pragma unroll
  for (int s = 0; s < 18; ++s) A[s] = *(const bf16x8*)(ap + s * 512);

  f32x4 acc[8];
#pragma unroll
  for (int t = 0; t < 8; ++t) acc[t] = (f32x4){0.f, 0.f, 0.f, 0.f};

  for (int tc = 0; tc < 4; ++tc) {
    __syncthreads();  // protect previous chunk's reads
    // stage fT rows [tc*32, +32), cols [ks*576, +576): 2304 16B-granules
#pragma unroll
    for (int it = 0; it < 9; ++it) {
      int idx = tid + it * 256;
      int c = idx / 72;  // 72 granules per row
      int g = idx - c * 72;
      *(bf16x8*)(&bt[c][g * 8]) =
          *(const bf16x8*)(fT + (tc * 32 + c) * 9216 + ks * 576 + g * 8);
    }
    __syncthreads();
#pragma unroll
    for (int tl = 0; tl < 2; ++tl) {
      const int t = tc * 2 + tl;
      const short* brow = &bt[tl * 16 + l15][q * 8];
#pragma unroll
      for (int s = 0; s < 18; ++s) {
        bf16x8 b = *(const bf16x8*)(brow + s * 32);
        acc[t] = __builtin_amdgcn_mfma_f32_16x16x32_bf16(A[s], b, acc[t], 0, 0, 0);
      }
    }
  }
#pragma unroll
  for (int t = 0; t < 8; ++t)
#pragma unroll
    for (int r = 0; r < 4; ++r)
      part[(ks * 1024 + jb + w * 16 + q * 4 + r) * 128 + t * 16 + l15] =
          acc[t][r];
}

// ---------------------------------------------------------------------------
// K3: fused projections, 1-wave MFMA blocks, grid (64, 11):
//   y==0: q = rowm @ q_w^T + q_b          -> qbuf  [i][c] fp32
//   y==1: k = colm @ k_w^T + k_b          -> khbuf [h][j][d] fp32
//         (colm built inline: fp32 sum of the 16 part slices, then bf16)
//   y>=2: v[m=y-2] = x @ v_w[l]^T (+b0)   -> vbT   [h][n][k=j] bf16
__global__ __launch_bounds__(64) void htr_proj(
    const short* __restrict__ rowm_bf, const float* __restrict__ part,
    const short* __restrict__ x_bf, const short* __restrict__ wbf,
    const float* __restrict__ q_b, const float* __restrict__ k_b,
    const float* __restrict__ v_b0, float* __restrict__ qbuf,
    float* __restrict__ khbuf, short* __restrict__ vbT) {
  const int ibase = blockIdx.x * 16;
  const int y = blockIdx.y;
  const int lane = threadIdx.x;
  const int q = lane >> 4, l15 = lane & 15;

  bf16x8 a[4];
  const short* bp;
  if (y == 0) {
    const short* ap = rowm_bf + (ibase + l15) * 128 + q * 8;
#pragma unroll
    for (int ks = 0; ks < 4; ++ks) a[ks] = *(const bf16x8*)(ap + ks * 32);
    bp = wbf + l15 * 128 + q * 8;
  } else if (y == 1) {
    const float* pp = part + (size_t)(ibase + l15) * 128;
#pragma unroll
    for (int ks = 0; ks < 4; ++ks) {
      float s0 = 0.f, s1 = 0.f, s2 = 0.f, s3 = 0.f;
      float s4 = 0.f, s5 = 0.f, s6 = 0.f, s7 = 0.f;
#pragma unroll
      for (int s = 0; s < CMS; ++s) {
        const float* ps = pp + s * 131072 + ks * 32 + q * 8;
        float4 u0 = *(const float4*)(ps);
        float4 u1 = *(const float4*)(ps + 4);
        s0 += u0.x; s1 += u0.y; s2 += u0.z; s3 += u0.w;
        s4 += u1.x; s5 += u1.y; s6 += u1.z; s7 += u1.w;
      }
      const float sc = 1.0f / 1024.0f;
      bf16x8 av;
      av[0] = f2bf(s0 * sc); av[1] = f2bf(s1 * sc);
      av[2] = f2bf(s2 * sc); av[3] = f2bf(s3 * sc);
      av[4] = f2bf(s4 * sc); av[5] = f2bf(s5 * sc);
      av[6] = f2bf(s6 * sc); av[7] = f2bf(s7 * sc);
      a[ks] = av;
    }
    bp = wbf + 16384 + l15 * 128 + q * 8;
  } else {
    const int m = y - 2;
    const int l = (m == 0) ? 0 : ((m < 4) ? 1 : 2);
    const short* ap = x_bf + ((ibase + l15) * 9 + m) * 128 + q * 8;
#pragma unroll
    for (int ks = 0; ks < 4; ++ks) a[ks] = *(const bf16x8*)(ap + ks * 32);
    bp = wbf + (2 + l) * 16384 + l15 * 128 + q * 8;
  }

  f32x4 acc[8];
#pragma unroll
  for (int t = 0; t < 8; ++t) {
    acc[t] = (f32x4){0.f, 0.f, 0.f, 0.f};
    const short* bt = bp + t * 2048;
#pragma unroll
    for (int ks = 0; ks < 4; ++ks) {
      bf16x8 b = *(const bf16x8*)(bt + ks * 32);
      acc[t] = __builtin_amdgcn_mfma_f32_16x16x32_bf16(a[ks], b, acc[t], 0, 0, 0);
    }
  }

  if (y == 0) {
#pragma unroll
    for (int t = 0; t < 8; ++t) {
      float bo = q_b[t * 16 + l15];
#pragma unroll
      for (int r = 0; r < 4; ++r)
        qbuf[(ibase + q * 4 + r) * 128 + t * 16 + l15] = acc[t][r] + bo;
    }
  } else if (y == 1) {
#pragma unroll
    for (int t = 0; t < 8; ++t) {
      float bo = k_b[t * 16 + l15];
#pragma unroll
      for (int r = 0; r < 4; ++r)
        khbuf[(t * 1024 + ibase + q * 4 + r) * 16 + l15] = acc[t][r] + bo;
    }
  } else {
    const int m = y - 2;
#pragma unroll
    for (int t = 0; t < 8; ++t) {
      float bias = (m == 0) ? v_b0[t * 16 + l15] : 0.f;
#pragma unroll
      for (int r = 0; r < 4; ++r)
        vbT[(t * 144 + m * 16 + l15) * 1024 + ibase + q * 4 + r] =
            f2bf(acc[t][r] + bias);
    }
  }
}

// ---------------------------------------------------------------------------
// K45 helper: apply phase for one wave, m-tiles [NT0, NT0+NT).
// P is the LDS score tile [16 rows][1024 j] bf16, XOR-swizzled:
// element (row, j) lives at P[row*1024 + (j ^ ((row&7)<<3))].
template <int NT0, int NT>
__device__ __forceinline__ void apply_phase(
    const short* P, const short* __restrict__ vbT,
    short* __restrict__ obuf_bf, int ibase, int h, int lane) {
  const int q = lane >> 4, l15 = lane & 15;
  const int xs = (l15 & 7) << 3;
  const short* pr = P + l15 * 1024;
  const short* bp = vbT + (h * 144 + l15) * 1024 + q * 8;
  f32x4 acc[NT];
#pragma unroll
  for (int t = 0; t < NT; ++t) acc[t] = (f32x4){0.f, 0.f, 0.f, 0.f};
  bf16x8 a = *(const bf16x8*)(pr + ((q * 8) ^ xs));
  bf16x8 b[NT];
#pragma unroll
  for (int t = 0; t < NT; ++t) b[t] = *(const bf16x8*)(bp + (NT0 + t) * 16384);
  for (int ks = 1; ks < 32; ++ks) {
    const int off = ks * 32;
    bf16x8 an = *(const bf16x8*)(pr + ((off + q * 8) ^ xs));
    bf16x8 bn[NT];
#pragma unroll
    for (int t = 0; t < NT; ++t)
      bn[t] = *(const bf16x8*)(bp + (NT0 + t) * 16384 + off);
#pragma unroll
    for (int t = 0; t < NT; ++t)
      acc[t] = __builtin_amdgcn_mfma_f32_16x16x32_bf16(a, b[t], acc[t], 0, 0, 0);
    a = an;
#pragma unroll
    for (int t = 0; t < NT; ++t) b[t] = bn[t];
  }
#pragma unroll
  for (int t = 0; t < NT; ++t)
    acc[t] = __builtin_amdgcn_mfma_f32_16x16x32_bf16(a, b[t], acc[t], 0, 0, 0);
#pragma unroll
  for (int t = 0; t < NT; ++t)
#pragma unroll
    for (int r = 0; r < 4; ++r)
      obuf_bf[((ibase + q * 4 + r) * 9 + NT0 + t) * 128 + h * 16 + l15] =
          f2bf(acc[t][r]);
}

// ---------------------------------------------------------------------------
// K45: fused attention + apply (flash-style; attn tensor never hits HBM).
// grid (64, 8), 256 threads. Phase 1: wave w owns q-rows w*4..w*4+3 fully
// (all 1024 j), softmax per-wave, normalized P -> LDS bf16 (swizzled).
// Phase 2: waves split the 9 m-tiles 3/2/2/2 and run the MFMA loop
// with the A-operand from LDS.
__global__ __launch_bounds__(256) void htr_attn_apply(
    const float* __restrict__ qbuf, const float* __restrict__ khbuf,
    const int* __restrict__ batch, const short* __restrict__ vbT,
    short* __restrict__ obuf_bf) {
  const int ibase = blockIdx.x * 16;
  const int h = blockIdx.y;
  const int tid = threadIdx.x;
  const int w = tid >> 6;
  const int lane = tid & 63;
  __shared__ short P[16 * 1024];

  // ---- phase 1: scores + softmax for this wave's 4 rows ----
  const int r0 = ibase + w * 4;
  float qr[4][16];
  int bi[4];
#pragma unroll
  for (int r = 0; r < 4; ++r) {
    bi[r] = batch[r0 + r];
    const float* qp = qbuf + (r0 + r) * 128 + h * 16;
#pragma unroll
    for (int d = 0; d < 16; ++d) qr[r][d] = qp[d] * 0.25f;
  }
  float s[4][16];
#pragma unroll
  for (int jt = 0; jt < 16; ++jt) {
    const int j = jt * 64 + lane;
    const int bj = batch[j];
    const float4* kp = (const float4*)(khbuf + (h * 1024 + j) * 16);
    float4 k0 = kp[0], k1 = kp[1], k2 = kp[2], k3 = kp[3];
#pragma unroll
    for (int r = 0; r < 4; ++r) {
      float d = 0.f;
      d = fmaf(qr[r][0], k0.x, d);  d = fmaf(qr[r][1], k0.y, d);
      d = fmaf(qr[r][2], k0.z, d);  d = fmaf(qr[r][3], k0.w, d);
      d = fmaf(qr[r][4], k1.x, d);  d = fmaf(qr[r][5], k1.y, d);
      d = fmaf(qr[r][6], k1.z, d);  d = fmaf(qr[r][7], k1.w, d);
      d = fmaf(qr[r][8], k2.x, d);  d = fmaf(qr[r][9], k2.y, d);
      d = fmaf(qr[r][10], k2.z, d); d = fmaf(qr[r][11], k2.w, d);
      d = fmaf(qr[r][12], k3.x, d); d = fmaf(qr[r][13], k3.y, d);
      d = fmaf(qr[r][14], k3.z, d); d = fmaf(qr[r][15], k3.w, d);
      s[r][jt] = (bj == bi[r]) ? d : -INFINITY;
    }
  }
#pragma unroll
  for (int r = 0; r < 4; ++r) {
    float mx = s[r][0];
#pragma unroll
    for (int jt = 1; jt < 16; ++jt) mx = fmaxf(mx, s[r][jt]);
    mx = wave_max(mx);
    mx = __shfl(mx, 0);
    float t = 0.f;
#pragma unroll
    for (int jt = 0; jt < 16; ++jt) {
      s[r][jt] = expf(s[r][jt] - mx);
      t += s[r][jt];
    }
    t = wave_sum(t);
    t = __shfl(t, 0);
    const float inv = 1.0f / t;
    const int row = w * 4 + r;
    const int xs = (row & 7) << 3;
    short* pw = P + row * 1024;
#pragma unroll
    for (int jt = 0; jt < 16; ++jt) {
      const int j = jt * 64 + lane;
      pw[j ^ xs] = f2bf(s[r][jt] * inv);
    }
  }
  __syncthreads();

  // ---- phase 2: apply, m-tiles split 3/2/2/2 across the 4 waves ----
  if (w == 0)      apply_phase<0, 3>(P, vbT, obuf_bf, ibase, h, lane);
  else if (w == 1) apply_phase<3, 2>(P, vbT, obuf_bf, ibase, h, lane);
  else if (w == 2) apply_phase<5, 2>(P, vbT, obuf_bf, ibase, h, lane);
  else             apply_phase<7, 2>(P, vbT, obuf_bf, ibase, h, lane);
}

// ---------------------------------------------------------------------------
// K6: out-projection + residual + LayerNorm (fused MFMA epilogue).
__global__ __launch_bounds__(64) void htr_outln_mfma(
    const short* __restrict__ obuf_bf, const float* __restrict__ x_emb,
    const short* __restrict__ wbf, const float* __restrict__ ln_g,
    const float* __restrict__ ln_b, float* __restrict__ out) {
  const int ibase = blockIdx.x * 16;
  const int m = blockIdx.y;
  const int l = (m == 0) ? 0 : ((m < 4) ? 1 : 2);
  const int lane = threadIdx.x;
  const int q = lane >> 4, l15 = lane & 15;
  const short* ap = obuf_bf + ((ibase + l15) * 9 + m) * 128 + q * 8;
  const short* bp = wbf + (5 + l) * 16384 + l15 * 128 + q * 8;
  bf16x8 a[4];
#pragma unroll
  for (int ks = 0; ks < 4; ++ks) a[ks] = *(const bf16x8*)(ap + ks * 32);
  f32x4 acc[8];
#pragma unroll
  for (int t = 0; t < 8; ++t) {
    acc[t] = (f32x4){0.f, 0.f, 0.f, 0.f};
    const short* bt = bp + t * 2048;
#pragma unroll
    for (int ks = 0; ks < 4; ++ks) {
      bf16x8 b = *(const bf16x8*)(bt + ks * 32);
      acc[t] = __builtin_amdgcn_mfma_f32_16x16x32_bf16(a[ks], b, acc[t], 0, 0, 0);
    }
  }
  float g[8], bb[8];
#pragma unroll
  for (int t = 0; t < 8; ++t) {
    g[t] = ln_g[l * 128 + t * 16 + l15];
    bb[t] = ln_b[l * 128 + t * 16 + l15];
  }
#pragma unroll
  for (int r = 0; r < 4; ++r) {
    const int i = ibase + q * 4 + r;
    const float* xr = x_emb + (i * 9 + m) * 128;
    float v[8];
    float sv = 0.f, sq = 0.f;
#pragma unroll
    for (int t = 0; t < 8; ++t) {
      v[t] = acc[t][r] + xr[t * 16 + l15];
      sv += v[t];
      sq += v[t] * v[t];
    }
#pragma unroll
    for (int off = 1; off < 16; off <<= 1) {
      sv += __shfl_xor(sv, off);
      sq += __shfl_xor(sq, off);
    }
    float mu = sv * (1.f / 128.f);
    float var = sq * (1.f / 128.f) - mu * mu;
    float rs = rsqrtf(var + 1e-5f);
    float* orow = out + (i * 9 + m) * 128;
#pragma unroll
    for (int t = 0; t < 8; ++t)
      orow[t * 16 + l15] = (v[t] - mu) * rs * g[t] + bb[t];
  }
}

// ---------------------------------------------------------------------------
extern "C" void kernel_launch(void* const* d_in, const int* in_sizes, int n_in,
                              void* d_out, int out_size, void* d_ws, size_t ws_size,
                              hipStream_t stream) {
  (void)in_sizes; (void)n_in; (void)out_size; (void)ws_size;
  const float* x_emb = (const float*)d_in[0];
  const float* pos   = (const float*)d_in[1];
  const float* q_w   = (const float*)d_in[2];
  const float* q_b   = (const float*)d_in[3];
  const float* k_w   = (const float*)d_in[4];
  const float* k_b   = (const float*)d_in[5];
  const float* v_w   = (const float*)d_in[6];
  const float* v_b0  = (const float*)d_in[7];
  const float* out_w = (const float*)d_in[8];
  const float* ln_g  = (const float*)d_in[9];
  const float* ln_b  = (const float*)d_in[10];
  const int*   batch = (const int*)d_in[11];
  float* out = (float*)d_out;

  // workspace (float-slot offsets; total 11,665,408 f = 46.7 MB).
  // Wpack occupies the former Wsh slot (same 9,437,184 bf16 size).
  float* ws = (float*)d_ws;
  short* rowm_bf = (short*)(ws + 0);         //   131,072 bf16
  float* qbuf    = ws + 65536;               //   131,072 f
  float* khbuf   = ws + 196608;              //   131,072 f  [h][j][d]
  short* wbf     = (short*)(ws + 327680);    //   131,072 bf16 (8 mats)
  short* x_bf    = (short*)(ws + 393216);    // 1,179,648 bf16
  short* vbT     = (short*)(ws + 983040);    // 1,179,648 bf16 [h][n][k]
  short* obuf_bf = (short*)(ws + 1572864);   // 1,179,648 bf16
  float* part    = ws + 2162688;             // 2,097,152 f
  short* Wpack   = (short*)(ws + 6356992);   // 9,437,184 bf16 (fragment order)
  short* fT      = (short*)(ws + 11075584);  // 1,179,648 bf16

  htr_geom<<<3496, 256, 0, stream>>>(q_w, k_w, v_w, out_w, x_emb, pos, batch,
                                     wbf, x_bf, fT, Wpack, rowm_bf);
  htr_colmean_mfma<<<dim3(16, CMS), 256, 0, stream>>>(Wpack, fT, part);
  htr_proj<<<dim3(64, 11), 64, 0, stream>>>(rowm_bf, part, x_bf, wbf, q_b, k_b,
                                            v_b0, qbuf, khbuf, vbT);
  htr_attn_apply<<<dim3(64, 8), 256, 0, stream>>>(qbuf, khbuf, batch, vbT,
                                                  obuf_bf);
  htr_outln_mfma<<<dim3(64, 9), 64, 0, stream>>>(obuf_bf, x_emb, wbf, ln_g,
                                                 ln_b, out);
}

// Round 8
// 152.568 us; speedup vs baseline: 1.0531x; 1.0531x over previous
//
#include <hip/hip_runtime.h>
#include <hip/hip_bf16.h>
#include <math.h>

#define NN 1024

typedef __attribute__((ext_vector_type(8))) short bf16x8;
typedef __attribute__((ext_vector_type(4))) float f32x4;

__device__ __forceinline__ float wave_sum(float v) {
#pragma unroll
  for (int off = 32; off > 0; off >>= 1) v += __shfl_down(v, off);
  return v;
}
__device__ __forceinline__ float wave_max(float v) {
#pragma unroll
  for (int off = 32; off > 0; off >>= 1) v = fmaxf(v, __shfl_down(v, off));
  return v;
}
__device__ __forceinline__ short f2bf(float x) {
  __hip_bfloat16 b = __float2bfloat16(x);
  return *(short*)&b;
}

#define SH_C0 0.28209479177387814f
#define SH_C1 0.4886025119029199f
#define SH_S15 1.0925484305920792f
#define SH_S5 0.6307831305050401f

// ---------------------------------------------------------------------------
// K1: fused independent staging. Block ranges:
//   [0,8)        : 8 weight mats fp32 -> bf16 (order q,k,v0,v1,v2,o0,o1,o2)
//   [8,1160)     : x_emb -> bf16 (x_bf)
//   [1160,1448)  : fkT[c'][k=m*1024+i] = bf16 of (x @ k_w^T), fT-layout.
//                  Replaces the old fT branch: projecting BEFORE colmean
//                  lets colmean emit khbuf directly (kproj dispatch dies).
//   [1448,2472)  : Wsh[j][k=m*1024+i] bf16 (sh*idg*valid folded) — R6 form
//                  (contiguous plane stores; R7's fragment-order scatter
//                  store regressed +8us).
//   [2472,3496)  : row stats + fused rowmean -> rowm_bf (bf16)
//   [3496,3500)  : khbuf init to k_b (colmean atomically accumulates on top)
__global__ __launch_bounds__(256) void htr_geom(
    const float* __restrict__ qw, const float* __restrict__ kw,
    const float* __restrict__ vw, const float* __restrict__ ow,
    const float* __restrict__ x_emb, const float* __restrict__ pos,
    const int* __restrict__ batch, const float* __restrict__ k_b,
    short* __restrict__ wbf, short* __restrict__ x_bf,
    short* __restrict__ fkT, short* __restrict__ Wsh,
    short* __restrict__ rowm_bf, float* __restrict__ khbuf) {
  const int b = blockIdx.x;
  const int tid = threadIdx.x;
  __shared__ short tile[128][36];
  __shared__ float red[4][9];
  __shared__ float sm[9];

  if (b < 8) {
    const float* src;
    if (b == 0) src = qw;
    else if (b == 1) src = kw;
    else if (b < 5) src = vw + (b - 2) * 16384;
    else src = ow + (b - 5) * 16384;
    short* dst = wbf + b * 16384;
    for (int idx = tid; idx < 16384; idx += 256) dst[idx] = f2bf(src[idx]);
  } else if (b < 1160) {
    int base = (b - 8) * 1024 + tid * 4;
    float4 v = *(const float4*)(x_emb + base);
    *(short4*)(x_bf + base) = make_short4(f2bf(v.x), f2bf(v.y), f2bf(v.z), f2bf(v.w));
  } else if (b < 1448) {
    // fkT branch: block = (m, 32-row i-group); 4 waves each do
    // 16 i x 64 c' (4 t-tiles x 4 ks of 16x16x32 MFMA), then LDS-transpose.
    const int sub = b - 1160;
    const int i0 = (sub & 31) * 32;
    const int m = sub >> 5;
    const int w = tid >> 6, lane = tid & 63;
    const int q = lane >> 4, l15 = lane & 15;
    const int isub = (w & 1) * 16;
    const int cbase = (w >> 1) * 64;
    bf16x8 a[4];
#pragma unroll
    for (int ks = 0; ks < 4; ++ks) {
      const float* ap = x_emb + ((i0 + isub + l15) * 9 + m) * 128 + ks * 32 + q * 8;
      bf16x8 av;
#pragma unroll
      for (int e = 0; e < 8; ++e) av[e] = f2bf(ap[e]);
      a[ks] = av;
    }
#pragma unroll
    for (int t = 0; t < 4; ++t) {
      f32x4 acc = (f32x4){0.f, 0.f, 0.f, 0.f};
#pragma unroll
      for (int ks = 0; ks < 4; ++ks) {
        const float* bp = kw + (cbase + t * 16 + l15) * 128 + ks * 32 + q * 8;
        bf16x8 bv;
#pragma unroll
        for (int e = 0; e < 8; ++e) bv[e] = f2bf(bp[e]);
        acc = __builtin_amdgcn_mfma_f32_16x16x32_bf16(a[ks], bv, acc, 0, 0, 0);
      }
#pragma unroll
      for (int r = 0; r < 4; ++r)
        tile[cbase + t * 16 + l15][isub + q * 4 + r] = f2bf(acc[r]);
    }
    __syncthreads();
    const int cc = tid >> 1, seg = tid & 1;
    short* dst = fkT + cc * 9216 + m * 1024 + i0 + seg * 16;
#pragma unroll
    for (int e = 0; e < 16; e += 2)
      *(short2*)(dst + e) = *(const short2*)(&tile[cc][seg * 16 + e]);
  } else if (b < 2472) {
    const int j = b - 1448;
    const float pjx = pos[j * 3 + 0], pjy = pos[j * 3 + 1], pjz = pos[j * 3 + 2];
    const int bj = batch[j];
    short* wrow = Wsh + j * 9216;
    for (int i = tid; i < 1024; i += 256) {
      float dx = pos[i * 3 + 0] - pjx;
      float dy = pos[i * 3 + 1] - pjy;
      float dz = pos[i * 3 + 2] - pjz;
      bool ok = (i != j) && (batch[i] == bj);
      float okf = ok ? 1.f : 0.f;
      float d2 = dx * dx + dy * dy + dz * dz;
      float inv = okf / fmaxf(sqrtf(d2), 1e-8f);
      float x = dx * inv, y = dy * inv, z = dz * inv;
      wrow[0 * 1024 + i] = f2bf(SH_C0 * okf);
      wrow[1 * 1024 + i] = f2bf((SH_C1 * (1.f / 3.f)) * x);
      wrow[2 * 1024 + i] = f2bf((SH_C1 * (1.f / 3.f)) * y);
      wrow[3 * 1024 + i] = f2bf((SH_C1 * (1.f / 3.f)) * z);
      wrow[4 * 1024 + i] = f2bf((SH_S15 * 0.2f) * x * z);
      wrow[5 * 1024 + i] = f2bf((SH_S15 * 0.2f) * x * y);
      wrow[6 * 1024 + i] = f2bf((SH_S5 * 0.2f) * (y * y - 0.5f * (x * x + z * z)));
      wrow[7 * 1024 + i] = f2bf((SH_S15 * 0.2f) * y * z);
      wrow[8 * 1024 + i] = f2bf((0.5f * SH_S15 * 0.2f) * (z * z - x * x));
    }
  } else if (b < 3496) {
    const int i = b - 2472;
    const float px = pos[i * 3 + 0], py = pos[i * 3 + 1], pz = pos[i * 3 + 2];
    const int bi = batch[i];
    float s[9];
#pragma unroll
    for (int m = 0; m < 9; ++m) s[m] = 0.f;
    for (int j = tid; j < NN; j += 256) {
      if (j == i) continue;
      if (batch[j] != bi) continue;
      float dx = px - pos[j * 3 + 0];
      float dy = py - pos[j * 3 + 1];
      float dz = pz - pos[j * 3 + 2];
      float d2 = dx * dx + dy * dy + dz * dz;
      float inv = 1.0f / fmaxf(sqrtf(d2), 1e-8f);
      float x = dx * inv, y = dy * inv, z = dz * inv;
      s[0] += 1.0f;
      s[1] += x; s[2] += y; s[3] += z;
      s[4] += x * z; s[5] += x * y;
      s[6] += y * y - 0.5f * (x * x + z * z);
      s[7] += y * z;
      s[8] += z * z - x * x;
    }
    const int wave = tid >> 6, lane = tid & 63;
#pragma unroll
    for (int m = 0; m < 9; ++m) {
      float v = wave_sum(s[m]);
      if (lane == 0) red[wave][m] = v;
    }
    __syncthreads();
    if (tid < 9) {
      float v = red[0][tid] + red[1][tid] + red[2][tid] + red[3][tid];
      float scl = SH_S15 * 0.2f;
      if (tid == 0) scl = SH_C0;
      else if (tid < 4) scl = SH_C1 * (1.f / 3.f);
      else if (tid == 6) scl = SH_S5 * 0.2f;
      else if (tid == 8) scl = 0.5f * SH_S15 * 0.2f;
      sm[tid] = v * scl * (1.0f / 1024.0f);
    }
    __syncthreads();
    if (tid < 128) {
      float acc = 0.f;
#pragma unroll
      for (int m = 0; m < 9; ++m)
        acc = fmaf(sm[m], x_emb[(i * 9 + m) * 128 + tid], acc);
      rowm_bf[i * 128 + tid] = f2bf(acc);
    }
  } else {
    // khbuf[h][j][d] = k_b[h*16+d]; colmean adds on top atomically.
    const int base = (b - 3496) * 32768;
    for (int u = tid; u < 32768; u += 256) {
      const int idx = base + u;
      khbuf[idx] = k_b[((idx >> 14) << 4) | (idx & 15)];
    }
  }
}

// ---------------------------------------------------------------------------
// K2: fused mid-stage, grid 416 x 256 threads (5 -> 4 dispatches):
//   b < 256   : colmean-k — R6's 4-wave LDS-staged colmean GEMM, B = fkT,
//               atomicAdd of acc/1024 into khbuf (pre-init'd to k_b by K1).
//               This replaces part + the 16-slice kproj gather entirely.
//   b in [256,272) : q-proj (rowm_bf @ q_w^T + q_b) -> qbuf, 4 wave-units/blk
//   b in [272,416) : v-proj (x_bf @ v_w^T (+b0))    -> vbT,  4 wave-units/blk
__global__ __launch_bounds__(256) void htr_mid(
    const short* __restrict__ Wsh, const short* __restrict__ fkT,
    const short* __restrict__ rowm_bf, const short* __restrict__ x_bf,
    const short* __restrict__ wbf, const float* __restrict__ q_b,
    const float* __restrict__ v_b0, float* __restrict__ khbuf,
    float* __restrict__ qbuf, short* __restrict__ vbT) {
  const int b = blockIdx.x;
  const int tid = threadIdx.x;
  const int w = tid >> 6, lane = tid & 63;
  const int q = lane >> 4, l15 = lane & 15;
  __shared__ short bt[32][584];

  if (b < 256) {
    const int jb = (b & 15) * 64;
    const int ks = b >> 4;
    const int j = jb + w * 16 + l15;
    const short* ap = Wsh + j * 9216 + ks * 576 + q * 8;
    bf16x8 A[18];
#pragma unroll
    for (int s = 0; s < 18; ++s) A[s] = *(const bf16x8*)(ap + s * 32);

    f32x4 acc[8];
#pragma unroll
    for (int t = 0; t < 8; ++t) acc[t] = (f32x4){0.f, 0.f, 0.f, 0.f};

    for (int tc = 0; tc < 4; ++tc) {
      __syncthreads();
#pragma unroll
      for (int it = 0; it < 9; ++it) {
        int idx = tid + it * 256;
        int c = idx / 72;
        int g = idx - c * 72;
        *(bf16x8*)(&bt[c][g * 8]) =
            *(const bf16x8*)(fkT + (tc * 32 + c) * 9216 + ks * 576 + g * 8);
      }
      __syncthreads();
#pragma unroll
      for (int tl = 0; tl < 2; ++tl) {
        const int t = tc * 2 + tl;
        const short* brow = &bt[tl * 16 + l15][q * 8];
#pragma unroll
        for (int s = 0; s < 18; ++s) {
          bf16x8 bv = *(const bf16x8*)(brow + s * 32);
          acc[t] = __builtin_amdgcn_mfma_f32_16x16x32_bf16(A[s], bv, acc[t], 0, 0, 0);
        }
      }
    }
#pragma unroll
    for (int t = 0; t < 8; ++t)
#pragma unroll
      for (int r = 0; r < 4; ++r)
        atomicAdd(&khbuf[(t * 1024 + jb + w * 16 + q * 4 + r) * 16 + l15],
                  acc[t][r] * (1.0f / 1024.0f));
  } else if (b < 272) {
    const int ibase = ((b - 256) * 4 + w) * 16;
    const short* ap = rowm_bf + (ibase + l15) * 128 + q * 8;
    const short* bp = wbf + l15 * 128 + q * 8;
    bf16x8 a[4];
#pragma unroll
    for (int ks = 0; ks < 4; ++ks) a[ks] = *(const bf16x8*)(ap + ks * 32);
    f32x4 acc[8];
#pragma unroll
    for (int t = 0; t < 8; ++t) {
      acc[t] = (f32x4){0.f, 0.f, 0.f, 0.f};
      const short* btp = bp + t * 2048;
#pragma unroll
      for (int ks = 0; ks < 4; ++ks) {
        bf16x8 bv = *(const bf16x8*)(btp + ks * 32);
        acc[t] = __builtin_amdgcn_mfma_f32_16x16x32_bf16(a[ks], bv, acc[t], 0, 0, 0);
      }
    }
#pragma unroll
    for (int t = 0; t < 8; ++t) {
      float bo = q_b[t * 16 + l15];
#pragma unroll
      for (int r = 0; r < 4; ++r)
        qbuf[(ibase + q * 4 + r) * 128 + t * 16 + l15] = acc[t][r] + bo;
    }
  } else {
    const int u = (b - 272) * 4 + w;
    const int m = u >> 6;
    const int ibase = (u & 63) * 16;
    const int l = (m == 0) ? 0 : ((m < 4) ? 1 : 2);
    const short* ap = x_bf + ((ibase + l15) * 9 + m) * 128 + q * 8;
    const short* bp = wbf + (2 + l) * 16384 + l15 * 128 + q * 8;
    bf16x8 a[4];
#pragma unroll
    for (int ks = 0; ks < 4; ++ks) a[ks] = *(const bf16x8*)(ap + ks * 32);
    f32x4 acc[8];
#pragma unroll
    for (int t = 0; t < 8; ++t) {
      acc[t] = (f32x4){0.f, 0.f, 0.f, 0.f};
      const short* btp = bp + t * 2048;
#pragma unroll
      for (int ks = 0; ks < 4; ++ks) {
        bf16x8 bv = *(const bf16x8*)(btp + ks * 32);
        acc[t] = __builtin_amdgcn_mfma_f32_16x16x32_bf16(a[ks], bv, acc[t], 0, 0, 0);
      }
    }
#pragma unroll
    for (int t = 0; t < 8; ++t) {
      float bias = (m == 0) ? v_b0[t * 16 + l15] : 0.f;
#pragma unroll
      for (int r = 0; r < 4; ++r)
        vbT[(t * 144 + m * 16 + l15) * 1024 + ibase + q * 4 + r] =
            f2bf(acc[t][r] + bias);
    }
  }
}

// ---------------------------------------------------------------------------
// K45 helper: apply phase for one wave, m-tiles [NT0, NT0+NT).
// P is the LDS score tile [16 rows][1024 j] bf16, XOR-swizzled:
// element (row, j) lives at P[row*1024 + (j ^ ((row&7)<<3))].
template <int NT0, int NT>
__device__ __forceinline__ void apply_phase(
    const short* P, const short* __restrict__ vbT,
    short* __restrict__ obuf_bf, int ibase, int h, int lane) {
  const int q = lane >> 4, l15 = lane & 15;
  const int xs = (l15 & 7) << 3;
  const short* pr = P + l15 * 1024;
  const short* bp = vbT + (h * 144 + l15) * 1024 + q * 8;
  f32x4 acc[NT];
#pragma unroll
  for (int t = 0; t < NT; ++t) acc[t] = (f32x4){0.f, 0.f, 0.f, 0.f};
  bf16x8 a = *(const bf16x8*)(pr + ((q * 8) ^ xs));
  bf16x8 b[NT];
#pragma unroll
  for (int t = 0; t < NT; ++t) b[t] = *(const bf16x8*)(bp + (NT0 + t) * 16384);
  for (int ks = 1; ks < 32; ++ks) {
    const int off = ks * 32;
    bf16x8 an = *(const bf16x8*)(pr + ((off + q * 8) ^ xs));
    bf16x8 bn[NT];
#pragma unroll
    for (int t = 0; t < NT; ++t)
      bn[t] = *(const bf16x8*)(bp + (NT0 + t) * 16384 + off);
#pragma unroll
    for (int t = 0; t < NT; ++t)
      acc[t] = __builtin_amdgcn_mfma_f32_16x16x32_bf16(a, b[t], acc[t], 0, 0, 0);
    a = an;
#pragma unroll
    for (int t = 0; t < NT; ++t) b[t] = bn[t];
  }
#pragma unroll
  for (int t = 0; t < NT; ++t)
    acc[t] = __builtin_amdgcn_mfma_f32_16x16x32_bf16(a, b[t], acc[t], 0, 0, 0);
#pragma unroll
  for (int t = 0; t < NT; ++t)
#pragma unroll
    for (int r = 0; r < 4; ++r)
      obuf_bf[((ibase + q * 4 + r) * 9 + NT0 + t) * 128 + h * 16 + l15] =
          f2bf(acc[t][r]);
}

// ---------------------------------------------------------------------------
// K45: fused attention + apply (flash-style; attn tensor never hits HBM).
// grid (64, 8), 256 threads.
__global__ __launch_bounds__(256) void htr_attn_apply(
    const float* __restrict__ qbuf, const float* __restrict__ khbuf,
    const int* __restrict__ batch, const short* __restrict__ vbT,
    short* __restrict__ obuf_bf) {
  const int ibase = blockIdx.x * 16;
  const int h = blockIdx.y;
  const int tid = threadIdx.x;
  const int w = tid >> 6;
  const int lane = tid & 63;
  __shared__ short P[16 * 1024];

  const int r0 = ibase + w * 4;
  float qr[4][16];
  int bi[4];
#pragma unroll
  for (int r = 0; r < 4; ++r) {
    bi[r] = batch[r0 + r];
    const float* qp = qbuf + (r0 + r) * 128 + h * 16;
#pragma unroll
    for (int d = 0; d < 16; ++d) qr[r][d] = qp[d] * 0.25f;
  }
  float s[4][16];
#pragma unroll
  for (int jt = 0; jt < 16; ++jt) {
    const int j = jt * 64 + lane;
    const int bj = batch[j];
    const float4* kp = (const float4*)(khbuf + (h * 1024 + j) * 16);
    float4 k0 = kp[0], k1 = kp[1], k2 = kp[2], k3 = kp[3];
#pragma unroll
    for (int r = 0; r < 4; ++r) {
      float d = 0.f;
      d = fmaf(qr[r][0], k0.x, d);  d = fmaf(qr[r][1], k0.y, d);
      d = fmaf(qr[r][2], k0.z, d);  d = fmaf(qr[r][3], k0.w, d);
      d = fmaf(qr[r][4], k1.x, d);  d = fmaf(qr[r][5], k1.y, d);
      d = fmaf(qr[r][6], k1.z, d);  d = fmaf(qr[r][7], k1.w, d);
      d = fmaf(qr[r][8], k2.x, d);  d = fmaf(qr[r][9], k2.y, d);
      d = fmaf(qr[r][10], k2.z, d); d = fmaf(qr[r][11], k2.w, d);
      d = fmaf(qr[r][12], k3.x, d); d = fmaf(qr[r][13], k3.y, d);
      d = fmaf(qr[r][14], k3.z, d); d = fmaf(qr[r][15], k3.w, d);
      s[r][jt] = (bj == bi[r]) ? d : -INFINITY;
    }
  }
#pragma unroll
  for (int r = 0; r < 4; ++r) {
    float mx = s[r][0];
#pragma unroll
    for (int jt = 1; jt < 16; ++jt) mx = fmaxf(mx, s[r][jt]);
    mx = wave_max(mx);
    mx = __shfl(mx, 0);
    float t = 0.f;
#pragma unroll
    for (int jt = 0; jt < 16; ++jt) {
      s[r][jt] = expf(s[r][jt] - mx);
      t += s[r][jt];
    }
    t = wave_sum(t);
    t = __shfl(t, 0);
    const float inv = 1.0f / t;
    const int row = w * 4 + r;
    const int xs = (row & 7) << 3;
    short* pw = P + row * 1024;
#pragma unroll
    for (int jt = 0; jt < 16; ++jt) {
      const int j = jt * 64 + lane;
      pw[j ^ xs] = f2bf(s[r][jt] * inv);
    }
  }
  __syncthreads();

  if (w == 0)      apply_phase<0, 3>(P, vbT, obuf_bf, ibase, h, lane);
  else if (w == 1) apply_phase<3, 2>(P, vbT, obuf_bf, ibase, h, lane);
  else if (w == 2) apply_phase<5, 2>(P, vbT, obuf_bf, ibase, h, lane);
  else             apply_phase<7, 2>(P, vbT, obuf_bf, ibase, h, lane);
}

// ---------------------------------------------------------------------------
// K6: out-projection + residual + LayerNorm (fused MFMA epilogue).
__global__ __launch_bounds__(64) void htr_outln_mfma(
    const short* __restrict__ obuf_bf, const float* __restrict__ x_emb,
    const short* __restrict__ wbf, const float* __restrict__ ln_g,
    const float* __restrict__ ln_b, float* __restrict__ out) {
  const int ibase = blockIdx.x * 16;
  const int m = blockIdx.y;
  const int l = (m == 0) ? 0 : ((m < 4) ? 1 : 2);
  const int lane = threadIdx.x;
  const int q = lane >> 4, l15 = lane & 15;
  const short* ap = obuf_bf + ((ibase + l15) * 9 + m) * 128 + q * 8;
  const short* bp = wbf + (5 + l) * 16384 + l15 * 128 + q * 8;
  bf16x8 a[4];
#pragma unroll
  for (int ks = 0; ks < 4; ++ks) a[ks] = *(const bf16x8*)(ap + ks * 32);
  f32x4 acc[8];
#pragma unroll
  for (int t = 0; t < 8; ++t) {
    acc[t] = (f32x4){0.f, 0.f, 0.f, 0.f};
    const short* bt = bp + t * 2048;
#pragma unroll
    for (int ks = 0; ks < 4; ++ks) {
      bf16x8 b = *(const bf16x8*)(bt + ks * 32);
      acc[t] = __builtin_amdgcn_mfma_f32_16x16x32_bf16(a[ks], b, acc[t], 0, 0, 0);
    }
  }
  float g[8], bb[8];
#pragma unroll
  for (int t = 0; t < 8; ++t) {
    g[t] = ln_g[l * 128 + t * 16 + l15];
    bb[t] = ln_b[l * 128 + t * 16 + l15];
  }
#pragma unroll
  for (int r = 0; r < 4; ++r) {
    const int i = ibase + q * 4 + r;
    const float* xr = x_emb + (i * 9 + m) * 128;
    float v[8];
    float sv = 0.f, sq = 0.f;
#pragma unroll
    for (int t = 0; t < 8; ++t) {
      v[t] = acc[t][r] + xr[t * 16 + l15];
      sv += v[t];
      sq += v[t] * v[t];
    }
#pragma unroll
    for (int off = 1; off < 16; off <<= 1) {
      sv += __shfl_xor(sv, off);
      sq += __shfl_xor(sq, off);
    }
    float mu = sv * (1.f / 128.f);
    float var = sq * (1.f / 128.f) - mu * mu;
    float rs = rsqrtf(var + 1e-5f);
    float* orow = out + (i * 9 + m) * 128;
#pragma unroll
    for (int t = 0; t < 8; ++t)
      orow[t * 16 + l15] = (v[t] - mu) * rs * g[t] + bb[t];
  }
}

// ---------------------------------------------------------------------------
extern "C" void kernel_launch(void* const* d_in, const int* in_sizes, int n_in,
                              void* d_out, int out_size, void* d_ws, size_t ws_size,
                              hipStream_t stream) {
  (void)in_sizes; (void)n_in; (void)out_size; (void)ws_size;
  const float* x_emb = (const float*)d_in[0];
  const float* pos   = (const float*)d_in[1];
  const float* q_w   = (const float*)d_in[2];
  const float* q_b   = (const float*)d_in[3];
  const float* k_w   = (const float*)d_in[4];
  const float* k_b   = (const float*)d_in[5];
  const float* v_w   = (const float*)d_in[6];
  const float* v_b0  = (const float*)d_in[7];
  const float* out_w = (const float*)d_in[8];
  const float* ln_g  = (const float*)d_in[9];
  const float* ln_b  = (const float*)d_in[10];
  const int*   batch = (const int*)d_in[11];
  float* out = (float*)d_out;

  // workspace (float-slot offsets). part buffer is dead (k goes straight
  // to khbuf via atomics); fkT reuses the old fT slot.
  float* ws = (float*)d_ws;
  short* rowm_bf = (short*)(ws + 0);         //   131,072 bf16
  float* qbuf    = ws + 65536;               //   131,072 f
  float* khbuf   = ws + 196608;              //   131,072 f  [h][j][d]
  short* wbf     = (short*)(ws + 327680);    //   131,072 bf16 (8 mats)
  short* x_bf    = (short*)(ws + 393216);    // 1,179,648 bf16
  short* vbT     = (short*)(ws + 983040);    // 1,179,648 bf16 [h][n][k]
  short* obuf_bf = (short*)(ws + 1572864);   // 1,179,648 bf16
  short* Wsh     = (short*)(ws + 6356992);   // 9,437,184 bf16
  short* fkT     = (short*)(ws + 11075584);  // 1,179,648 bf16

  htr_geom<<<3500, 256, 0, stream>>>(q_w, k_w, v_w, out_w, x_emb, pos, batch,
                                     k_b, wbf, x_bf, fkT, Wsh, rowm_bf, khbuf);
  htr_mid<<<416, 256, 0, stream>>>(Wsh, fkT, rowm_bf, x_bf, wbf, q_b, v_b0,
                                   khbuf, qbuf, vbT);
  htr_attn_apply<<<dim3(64, 8), 256, 0, stream>>>(qbuf, khbuf, batch, vbT,
                                                  obuf_bf);
  htr_outln_mfma<<<dim3(64, 9), 64, 0, stream>>>(obuf_bf, x_emb, wbf, ln_g,
                                                 ln_b, out);
}

// Round 9
// 151.576 us; speedup vs baseline: 1.0600x; 1.0065x over previous
//
#include <hip/hip_runtime.h>
#include <hip/hip_bf16.h>
#include <math.h>

#define NN 1024

typedef __attribute__((ext_vector_type(8))) short bf16x8;
typedef __attribute__((ext_vector_type(4))) float f32x4;

__device__ __forceinline__ float wave_sum(float v) {
#pragma unroll
  for (int off = 32; off > 0; off >>= 1) v += __shfl_down(v, off);
  return v;
}
__device__ __forceinline__ float wave_max(float v) {
#pragma unroll
  for (int off = 32; off > 0; off >>= 1) v = fmaxf(v, __shfl_down(v, off));
  return v;
}
__device__ __forceinline__ short f2bf(float x) {
  __hip_bfloat16 b = __float2bfloat16(x);
  return *(short*)&b;
}

#define SH_C0 0.28209479177387814f
#define SH_C1 0.4886025119029199f
#define SH_S15 1.0925484305920792f
#define SH_S5 0.6307831305050401f

// ---------------------------------------------------------------------------
// K1: fused independent staging. Block ranges (Wsh branch DELETED — colmean
// now generates its A-fragments on the fly with once-per-pair geometry):
//   [0,8)        : 8 weight mats fp32 -> bf16 (order q,k,v0,v1,v2,o0,o1,o2)
//   [8,1160)     : x_emb -> bf16 (x_bf)
//   [1160,1448)  : fkT[c'][k=m*1024+i] = bf16 of (x @ k_w^T), fT-layout
//   [1448,2472)  : row stats + fused rowmean -> rowm_bf (bf16)
//   [2472,2476)  : khbuf init to k_b (colmean atomically accumulates on top)
__global__ __launch_bounds__(256) void htr_geom(
    const float* __restrict__ qw, const float* __restrict__ kw,
    const float* __restrict__ vw, const float* __restrict__ ow,
    const float* __restrict__ x_emb, const float* __restrict__ pos,
    const int* __restrict__ batch, const float* __restrict__ k_b,
    short* __restrict__ wbf, short* __restrict__ x_bf,
    short* __restrict__ fkT, short* __restrict__ rowm_bf,
    float* __restrict__ khbuf) {
  const int b = blockIdx.x;
  const int tid = threadIdx.x;
  __shared__ short tile[128][36];
  __shared__ float red[4][9];
  __shared__ float sm[9];

  if (b < 8) {
    const float* src;
    if (b == 0) src = qw;
    else if (b == 1) src = kw;
    else if (b < 5) src = vw + (b - 2) * 16384;
    else src = ow + (b - 5) * 16384;
    short* dst = wbf + b * 16384;
    for (int idx = tid; idx < 16384; idx += 256) dst[idx] = f2bf(src[idx]);
  } else if (b < 1160) {
    int base = (b - 8) * 1024 + tid * 4;
    float4 v = *(const float4*)(x_emb + base);
    *(short4*)(x_bf + base) = make_short4(f2bf(v.x), f2bf(v.y), f2bf(v.z), f2bf(v.w));
  } else if (b < 1448) {
    // fkT branch: block = (m, 32-row i-group); 4 waves each do
    // 16 i x 64 c' (4 t-tiles x 4 ks of 16x16x32 MFMA), then LDS-transpose.
    const int sub = b - 1160;
    const int i0 = (sub & 31) * 32;
    const int m = sub >> 5;
    const int w = tid >> 6, lane = tid & 63;
    const int q = lane >> 4, l15 = lane & 15;
    const int isub = (w & 1) * 16;
    const int cbase = (w >> 1) * 64;
    bf16x8 a[4];
#pragma unroll
    for (int ks = 0; ks < 4; ++ks) {
      const float* ap = x_emb + ((i0 + isub + l15) * 9 + m) * 128 + ks * 32 + q * 8;
      bf16x8 av;
#pragma unroll
      for (int e = 0; e < 8; ++e) av[e] = f2bf(ap[e]);
      a[ks] = av;
    }
#pragma unroll
    for (int t = 0; t < 4; ++t) {
      f32x4 acc = (f32x4){0.f, 0.f, 0.f, 0.f};
#pragma unroll
      for (int ks = 0; ks < 4; ++ks) {
        const float* bp = kw + (cbase + t * 16 + l15) * 128 + ks * 32 + q * 8;
        bf16x8 bv;
#pragma unroll
        for (int e = 0; e < 8; ++e) bv[e] = f2bf(bp[e]);
        acc = __builtin_amdgcn_mfma_f32_16x16x32_bf16(a[ks], bv, acc, 0, 0, 0);
      }
#pragma unroll
      for (int r = 0; r < 4; ++r)
        tile[cbase + t * 16 + l15][isub + q * 4 + r] = f2bf(acc[r]);
    }
    __syncthreads();
    const int cc = tid >> 1, seg = tid & 1;
    short* dst = fkT + cc * 9216 + m * 1024 + i0 + seg * 16;
#pragma unroll
    for (int e = 0; e < 16; e += 2)
      *(short2*)(dst + e) = *(const short2*)(&tile[cc][seg * 16 + e]);
  } else if (b < 2472) {
    const int i = b - 1448;
    const float px = pos[i * 3 + 0], py = pos[i * 3 + 1], pz = pos[i * 3 + 2];
    const int bi = batch[i];
    float s[9];
#pragma unroll
    for (int m = 0; m < 9; ++m) s[m] = 0.f;
    for (int j = tid; j < NN; j += 256) {
      if (j == i) continue;
      if (batch[j] != bi) continue;
      float dx = px - pos[j * 3 + 0];
      float dy = py - pos[j * 3 + 1];
      float dz = pz - pos[j * 3 + 2];
      float d2 = dx * dx + dy * dy + dz * dz;
      float inv = 1.0f / fmaxf(sqrtf(d2), 1e-8f);
      float x = dx * inv, y = dy * inv, z = dz * inv;
      s[0] += 1.0f;
      s[1] += x; s[2] += y; s[3] += z;
      s[4] += x * z; s[5] += x * y;
      s[6] += y * y - 0.5f * (x * x + z * z);
      s[7] += y * z;
      s[8] += z * z - x * x;
    }
    const int wave = tid >> 6, lane = tid & 63;
#pragma unroll
    for (int m = 0; m < 9; ++m) {
      float v = wave_sum(s[m]);
      if (lane == 0) red[wave][m] = v;
    }
    __syncthreads();
    if (tid < 9) {
      float v = red[0][tid] + red[1][tid] + red[2][tid] + red[3][tid];
      float scl = SH_S15 * 0.2f;
      if (tid == 0) scl = SH_C0;
      else if (tid < 4) scl = SH_C1 * (1.f / 3.f);
      else if (tid == 6) scl = SH_S5 * 0.2f;
      else if (tid == 8) scl = 0.5f * SH_S15 * 0.2f;
      sm[tid] = v * scl * (1.0f / 1024.0f);
    }
    __syncthreads();
    if (tid < 128) {
      float acc = 0.f;
#pragma unroll
      for (int m = 0; m < 9; ++m)
        acc = fmaf(sm[m], x_emb[(i * 9 + m) * 128 + tid], acc);
      rowm_bf[i * 128 + tid] = f2bf(acc);
    }
  } else {
    // khbuf[h][j][d] = k_b[h*16+d]; colmean adds on top atomically.
    const int base = (b - 2472) * 32768;
    for (int u = tid; u < 32768; u += 256) {
      const int idx = base + u;
      khbuf[idx] = k_b[((idx >> 14) << 4) | (idx & 15)];
    }
  }
}

// ---------------------------------------------------------------------------
// K2: fused mid-stage, grid 416 x 256 threads:
//   b < 256   : colmean-k with ON-THE-FLY A-generation. Block = (jb, ib):
//               64 j's x (64 i's x 9 m's = 576 k's, m-major: kk=m*64+di).
//               Each lane computes geometry ONCE for its 16 (j,i) pairs
//               (R2's failure was 9x re-eval per m-plane; this decomposition
//               amortizes across m), expands 9 sh values into its 18
//               A-fragments (m = s>>1 is compile-time in the unrolled loop).
//               B = fkT staged via LDS (R6 structure, re-indexed granules).
//               acc/1024 atomicAdd'd into khbuf (pre-init'd to k_b by K1).
//               Wsh (18.9 MB write + 18.9 MB read) is GONE.
//   b in [256,272) : q-proj (rowm_bf @ q_w^T + q_b) -> qbuf
//   b in [272,416) : v-proj (x_bf @ v_w^T (+b0))    -> vbT
__global__ __launch_bounds__(256) void htr_mid(
    const float* __restrict__ pos, const int* __restrict__ batch,
    const short* __restrict__ fkT, const short* __restrict__ rowm_bf,
    const short* __restrict__ x_bf, const short* __restrict__ wbf,
    const float* __restrict__ q_b, const float* __restrict__ v_b0,
    float* __restrict__ khbuf, float* __restrict__ qbuf,
    short* __restrict__ vbT) {
  const int b = blockIdx.x;
  const int tid = threadIdx.x;
  const int w = tid >> 6, lane = tid & 63;
  const int q = lane >> 4, l15 = lane & 15;
  __shared__ short bt[32][584];
  __shared__ float4 pj_s[64], pi_s[64];

  if (b < 256) {
    const int jb = (b & 15) * 64;
    const int ib = (b >> 4) * 64;
    if (tid < 64)
      pj_s[tid] = make_float4(pos[(jb + tid) * 3 + 0], pos[(jb + tid) * 3 + 1],
                              pos[(jb + tid) * 3 + 2],
                              __int_as_float(batch[jb + tid]));
    else if (tid < 128) {
      const int u = tid - 64;
      pi_s[u] = make_float4(pos[(ib + u) * 3 + 0], pos[(ib + u) * 3 + 1],
                            pos[(ib + u) * 3 + 2],
                            __int_as_float(batch[ib + u]));
    }
    __syncthreads();

    const int jl = w * 16 + l15;       // local j
    const int j = jb + jl;
    const float4 pj = pj_s[jl];
    const int bj = __float_as_int(pj.w);

    // A-fragments: s = 2*m + half; element e -> i = ib + half*32 + q*8 + e.
    bf16x8 A[18];
    {
#pragma unroll
      for (int half = 0; half < 2; ++half) {
        float gx[8], gy[8], gz[8], go[8];
#pragma unroll
        for (int e = 0; e < 8; ++e) {
          const int il = half * 32 + q * 8 + e;
          const float4 pi = pi_s[il];
          const bool ok = ((ib + il) != j) && (__float_as_int(pi.w) == bj);
          const float okf = ok ? 1.f : 0.f;
          const float dx = pi.x - pj.x;
          const float dy = pi.y - pj.y;
          const float dz = pi.z - pj.z;
          const float d2 = dx * dx + dy * dy + dz * dz;
          const float inv = okf / fmaxf(sqrtf(d2), 1e-8f);
          gx[e] = dx * inv; gy[e] = dy * inv; gz[e] = dz * inv; go[e] = okf;
        }
#pragma unroll
        for (int e = 0; e < 8; ++e) {
          const float x = gx[e], y = gy[e], z = gz[e], okf = go[e];
          A[0 + half][e] = f2bf(SH_C0 * okf);
          A[2 + half][e] = f2bf((SH_C1 * (1.f / 3.f)) * x);
          A[4 + half][e] = f2bf((SH_C1 * (1.f / 3.f)) * y);
          A[6 + half][e] = f2bf((SH_C1 * (1.f / 3.f)) * z);
          A[8 + half][e] = f2bf((SH_S15 * 0.2f) * x * z);
          A[10 + half][e] = f2bf((SH_S15 * 0.2f) * x * y);
          A[12 + half][e] = f2bf((SH_S5 * 0.2f) * (y * y - 0.5f * (x * x + z * z)));
          A[14 + half][e] = f2bf((SH_S15 * 0.2f) * y * z);
          A[16 + half][e] = f2bf((0.5f * SH_S15 * 0.2f) * (z * z - x * x));
        }
      }
    }

    f32x4 acc[8];
#pragma unroll
    for (int t = 0; t < 8; ++t) acc[t] = (f32x4){0.f, 0.f, 0.f, 0.f};

    for (int tc = 0; tc < 4; ++tc) {
      __syncthreads();
      // stage fkT rows [tc*32,+32), k-cols {m*1024 + ib + di} m-major:
      // granule g (0..71): m = g>>3, di = (g&7)*8.
#pragma unroll
      for (int it = 0; it < 9; ++it) {
        int idx = tid + it * 256;
        int c = idx / 72;
        int g = idx - c * 72;
        *(bf16x8*)(&bt[c][g * 8]) =
            *(const bf16x8*)(fkT + (tc * 32 + c) * 9216 + (g >> 3) * 1024 + ib +
                             (g & 7) * 8);
      }
      __syncthreads();
#pragma unroll
      for (int tl = 0; tl < 2; ++tl) {
        const int t = tc * 2 + tl;
        const short* brow = &bt[tl * 16 + l15][q * 8];
#pragma unroll
        for (int s = 0; s < 18; ++s) {
          bf16x8 bv = *(const bf16x8*)(brow + s * 32);
          acc[t] = __builtin_amdgcn_mfma_f32_16x16x32_bf16(A[s], bv, acc[t], 0, 0, 0);
        }
      }
    }
#pragma unroll
    for (int t = 0; t < 8; ++t)
#pragma unroll
      for (int r = 0; r < 4; ++r)
        atomicAdd(&khbuf[(t * 1024 + jb + w * 16 + q * 4 + r) * 16 + l15],
                  acc[t][r] * (1.0f / 1024.0f));
  } else if (b < 272) {
    const int ibase = ((b - 256) * 4 + w) * 16;
    const short* ap = rowm_bf + (ibase + l15) * 128 + q * 8;
    const short* bp = wbf + l15 * 128 + q * 8;
    bf16x8 a[4];
#pragma unroll
    for (int ks = 0; ks < 4; ++ks) a[ks] = *(const bf16x8*)(ap + ks * 32);
    f32x4 acc[8];
#pragma unroll
    for (int t = 0; t < 8; ++t) {
      acc[t] = (f32x4){0.f, 0.f, 0.f, 0.f};
      const short* btp = bp + t * 2048;
#pragma unroll
      for (int ks = 0; ks < 4; ++ks) {
        bf16x8 bv = *(const bf16x8*)(btp + ks * 32);
        acc[t] = __builtin_amdgcn_mfma_f32_16x16x32_bf16(a[ks], bv, acc[t], 0, 0, 0);
      }
    }
#pragma unroll
    for (int t = 0; t < 8; ++t) {
      float bo = q_b[t * 16 + l15];
#pragma unroll
      for (int r = 0; r < 4; ++r)
        qbuf[(ibase + q * 4 + r) * 128 + t * 16 + l15] = acc[t][r] + bo;
    }
  } else {
    const int u = (b - 272) * 4 + w;
    const int m = u >> 6;
    const int ibase = (u & 63) * 16;
    const int l = (m == 0) ? 0 : ((m < 4) ? 1 : 2);
    const short* ap = x_bf + ((ibase + l15) * 9 + m) * 128 + q * 8;
    const short* bp = wbf + (2 + l) * 16384 + l15 * 128 + q * 8;
    bf16x8 a[4];
#pragma unroll
    for (int ks = 0; ks < 4; ++ks) a[ks] = *(const bf16x8*)(ap + ks * 32);
    f32x4 acc[8];
#pragma unroll
    for (int t = 0; t < 8; ++t) {
      acc[t] = (f32x4){0.f, 0.f, 0.f, 0.f};
      const short* btp = bp + t * 2048;
#pragma unroll
      for (int ks = 0; ks < 4; ++ks) {
        bf16x8 bv = *(const bf16x8*)(btp + ks * 32);
        acc[t] = __builtin_amdgcn_mfma_f32_16x16x32_bf16(a[ks], bv, acc[t], 0, 0, 0);
      }
    }
#pragma unroll
    for (int t = 0; t < 8; ++t) {
      float bias = (m == 0) ? v_b0[t * 16 + l15] : 0.f;
#pragma unroll
      for (int r = 0; r < 4; ++r)
        vbT[(t * 144 + m * 16 + l15) * 1024 + ibase + q * 4 + r] =
            f2bf(acc[t][r] + bias);
    }
  }
}

// ---------------------------------------------------------------------------
// K45 helper: apply phase for one wave, m-tiles [NT0, NT0+NT).
// P is the LDS score tile [16 rows][1024 j] bf16, XOR-swizzled:
// element (row, j) lives at P[row*1024 + (j ^ ((row&7)<<3))].
template <int NT0, int NT>
__device__ __forceinline__ void apply_phase(
    const short* P, const short* __restrict__ vbT,
    short* __restrict__ obuf_bf, int ibase, int h, int lane) {
  const int q = lane >> 4, l15 = lane & 15;
  const int xs = (l15 & 7) << 3;
  const short* pr = P + l15 * 1024;
  const short* bp = vbT + (h * 144 + l15) * 1024 + q * 8;
  f32x4 acc[NT];
#pragma unroll
  for (int t = 0; t < NT; ++t) acc[t] = (f32x4){0.f, 0.f, 0.f, 0.f};
  bf16x8 a = *(const bf16x8*)(pr + ((q * 8) ^ xs));
  bf16x8 b[NT];
#pragma unroll
  for (int t = 0; t < NT; ++t) b[t] = *(const bf16x8*)(bp + (NT0 + t) * 16384);
  for (int ks = 1; ks < 32; ++ks) {
    const int off = ks * 32;
    bf16x8 an = *(const bf16x8*)(pr + ((off + q * 8) ^ xs));
    bf16x8 bn[NT];
#pragma unroll
    for (int t = 0; t < NT; ++t)
      bn[t] = *(const bf16x8*)(bp + (NT0 + t) * 16384 + off);
#pragma unroll
    for (int t = 0; t < NT; ++t)
      acc[t] = __builtin_amdgcn_mfma_f32_16x16x32_bf16(a, b[t], acc[t], 0, 0, 0);
    a = an;
#pragma unroll
    for (int t = 0; t < NT; ++t) b[t] = bn[t];
  }
#pragma unroll
  for (int t = 0; t < NT; ++t)
    acc[t] = __builtin_amdgcn_mfma_f32_16x16x32_bf16(a, b[t], acc[t], 0, 0, 0);
#pragma unroll
  for (int t = 0; t < NT; ++t)
#pragma unroll
    for (int r = 0; r < 4; ++r)
      obuf_bf[((ibase + q * 4 + r) * 9 + NT0 + t) * 128 + h * 16 + l15] =
          f2bf(acc[t][r]);
}

// ---------------------------------------------------------------------------
// K45: fused attention + apply (flash-style; attn tensor never hits HBM).
// grid (64, 8), 256 threads.
__global__ __launch_bounds__(256) void htr_attn_apply(
    const float* __restrict__ qbuf, const float* __restrict__ khbuf,
    const int* __restrict__ batch, const short* __restrict__ vbT,
    short* __restrict__ obuf_bf) {
  const int ibase = blockIdx.x * 16;
  const int h = blockIdx.y;
  const int tid = threadIdx.x;
  const int w = tid >> 6;
  const int lane = tid & 63;
  __shared__ short P[16 * 1024];

  const int r0 = ibase + w * 4;
  float qr[4][16];
  int bi[4];
#pragma unroll
  for (int r = 0; r < 4; ++r) {
    bi[r] = batch[r0 + r];
    const float* qp = qbuf + (r0 + r) * 128 + h * 16;
#pragma unroll
    for (int d = 0; d < 16; ++d) qr[r][d] = qp[d] * 0.25f;
  }
  float s[4][16];
#pragma unroll
  for (int jt = 0; jt < 16; ++jt) {
    const int j = jt * 64 + lane;
    const int bj = batch[j];
    const float4* kp = (const float4*)(khbuf + (h * 1024 + j) * 16);
    float4 k0 = kp[0], k1 = kp[1], k2 = kp[2], k3 = kp[3];
#pragma unroll
    for (int r = 0; r < 4; ++r) {
      float d = 0.f;
      d = fmaf(qr[r][0], k0.x, d);  d = fmaf(qr[r][1], k0.y, d);
      d = fmaf(qr[r][2], k0.z, d);  d = fmaf(qr[r][3], k0.w, d);
      d = fmaf(qr[r][4], k1.x, d);  d = fmaf(qr[r][5], k1.y, d);
      d = fmaf(qr[r][6], k1.z, d);  d = fmaf(qr[r][7], k1.w, d);
      d = fmaf(qr[r][8], k2.x, d);  d = fmaf(qr[r][9], k2.y, d);
      d = fmaf(qr[r][10], k2.z, d); d = fmaf(qr[r][11], k2.w, d);
      d = fmaf(qr[r][12], k3.x, d); d = fmaf(qr[r][13], k3.y, d);
      d = fmaf(qr[r][14], k3.z, d); d = fmaf(qr[r][15], k3.w, d);
      s[r][jt] = (bj == bi[r]) ? d : -INFINITY;
    }
  }
#pragma unroll
  for (int r = 0; r < 4; ++r) {
    float mx = s[r][0];
#pragma unroll
    for (int jt = 1; jt < 16; ++jt) mx = fmaxf(mx, s[r][jt]);
    mx = wave_max(mx);
    mx = __shfl(mx, 0);
    float t = 0.f;
#pragma unroll
    for (int jt = 0; jt < 16; ++jt) {
      s[r][jt] = expf(s[r][jt] - mx);
      t += s[r][jt];
    }
    t = wave_sum(t);
    t = __shfl(t, 0);
    const float inv = 1.0f / t;
    const int row = w * 4 + r;
    const int xs = (row & 7) << 3;
    short* pw = P + row * 1024;
#pragma unroll
    for (int jt = 0; jt < 16; ++jt) {
      const int j = jt * 64 + lane;
      pw[j ^ xs] = f2bf(s[r][jt] * inv);
    }
  }
  __syncthreads();

  if (w == 0)      apply_phase<0, 3>(P, vbT, obuf_bf, ibase, h, lane);
  else if (w == 1) apply_phase<3, 2>(P, vbT, obuf_bf, ibase, h, lane);
  else if (w == 2) apply_phase<5, 2>(P, vbT, obuf_bf, ibase, h, lane);
  else             apply_phase<7, 2>(P, vbT, obuf_bf, ibase, h, lane);
}

// ---------------------------------------------------------------------------
// K6: out-projection + residual + LayerNorm (fused MFMA epilogue).
__global__ __launch_bounds__(64) void htr_outln_mfma(
    const short* __restrict__ obuf_bf, const float* __restrict__ x_emb,
    const short* __restrict__ wbf, const float* __restrict__ ln_g,
    const float* __restrict__ ln_b, float* __restrict__ out) {
  const int ibase = blockIdx.x * 16;
  const int m = blockIdx.y;
  const int l = (m == 0) ? 0 : ((m < 4) ? 1 : 2);
  const int lane = threadIdx.x;
  const int q = lane >> 4, l15 = lane & 15;
  const short* ap = obuf_bf + ((ibase + l15) * 9 + m) * 128 + q * 8;
  const short* bp = wbf + (5 + l) * 16384 + l15 * 128 + q * 8;
  bf16x8 a[4];
#pragma unroll
  for (int ks = 0; ks < 4; ++ks) a[ks] = *(const bf16x8*)(ap + ks * 32);
  f32x4 acc[8];
#pragma unroll
  for (int t = 0; t < 8; ++t) {
    acc[t] = (f32x4){0.f, 0.f, 0.f, 0.f};
    const short* bt = bp + t * 2048;
#pragma unroll
    for (int ks = 0; ks < 4; ++ks) {
      bf16x8 b = *(const bf16x8*)(bt + ks * 32);
      acc[t] = __builtin_amdgcn_mfma_f32_16x16x32_bf16(a[ks], b, acc[t], 0, 0, 0);
    }
  }
  float g[8], bb[8];
#pragma unroll
  for (int t = 0; t < 8; ++t) {
    g[t] = ln_g[l * 128 + t * 16 + l15];
    bb[t] = ln_b[l * 128 + t * 16 + l15];
  }
#pragma unroll
  for (int r = 0; r < 4; ++r) {
    const int i = ibase + q * 4 + r;
    const float* xr = x_emb + (i * 9 + m) * 128;
    float v[8];
    float sv = 0.f, sq = 0.f;
#pragma unroll
    for (int t = 0; t < 8; ++t) {
      v[t] = acc[t][r] + xr[t * 16 + l15];
      sv += v[t];
      sq += v[t] * v[t];
    }
#pragma unroll
    for (int off = 1; off < 16; off <<= 1) {
      sv += __shfl_xor(sv, off);
      sq += __shfl_xor(sq, off);
    }
    float mu = sv * (1.f / 128.f);
    float var = sq * (1.f / 128.f) - mu * mu;
    float rs = rsqrtf(var + 1e-5f);
    float* orow = out + (i * 9 + m) * 128;
#pragma unroll
    for (int t = 0; t < 8; ++t)
      orow[t * 16 + l15] = (v[t] - mu) * rs * g[t] + bb[t];
  }
}

// ---------------------------------------------------------------------------
extern "C" void kernel_launch(void* const* d_in, const int* in_sizes, int n_in,
                              void* d_out, int out_size, void* d_ws, size_t ws_size,
                              hipStream_t stream) {
  (void)in_sizes; (void)n_in; (void)out_size; (void)ws_size;
  const float* x_emb = (const float*)d_in[0];
  const float* pos   = (const float*)d_in[1];
  const float* q_w   = (const float*)d_in[2];
  const float* q_b   = (const float*)d_in[3];
  const float* k_w   = (const float*)d_in[4];
  const float* k_b   = (const float*)d_in[5];
  const float* v_w   = (const float*)d_in[6];
  const float* v_b0  = (const float*)d_in[7];
  const float* out_w = (const float*)d_in[8];
  const float* ln_g  = (const float*)d_in[9];
  const float* ln_b  = (const float*)d_in[10];
  const int*   batch = (const int*)d_in[11];
  float* out = (float*)d_out;

  // workspace (float-slot offsets). Wsh is GONE (on-the-fly A-gen in mid).
  float* ws = (float*)d_ws;
  short* rowm_bf = (short*)(ws + 0);         //   131,072 bf16
  float* qbuf    = ws + 65536;               //   131,072 f
  float* khbuf   = ws + 196608;              //   131,072 f  [h][j][d]
  short* wbf     = (short*)(ws + 327680);    //   131,072 bf16 (8 mats)
  short* x_bf    = (short*)(ws + 393216);    // 1,179,648 bf16
  short* vbT     = (short*)(ws + 983040);    // 1,179,648 bf16 [h][n][k]
  short* obuf_bf = (short*)(ws + 1572864);   // 1,179,648 bf16
  short* fkT     = (short*)(ws + 11075584);  // 1,179,648 bf16

  htr_geom<<<2476, 256, 0, stream>>>(q_w, k_w, v_w, out_w, x_emb, pos, batch,
                                     k_b, wbf, x_bf, fkT, rowm_bf, khbuf);
  htr_mid<<<416, 256, 0, stream>>>(pos, batch, fkT, rowm_bf, x_bf, wbf, q_b,
                                   v_b0, khbuf, qbuf, vbT);
  htr_attn_apply<<<dim3(64, 8), 256, 0, stream>>>(qbuf, khbuf, batch, vbT,
                                                  obuf_bf);
  htr_outln_mfma<<<dim3(64, 9), 64, 0, stream>>>(obuf_bf, x_emb, wbf, ln_g,
                                                 ln_b, out);
}